// Round 3
// baseline (444.924 us; speedup 1.0000x reference)
//
#include <hip/hip_runtime.h>

#define SEQ_LEN 16384
#define ENC_H   2048
#define DEC_H   2048
#define NBLK    1024
#define CHUNK   (SEQ_LEN / NBLK)     // 16 rows per block in phase 3
#define WTHR    1e-9f                // skip threshold; err <= 16384*1e-9*max|enc| ~ 1e-4

// Device-scope sense/generation barrier. Requires all NBLK blocks co-resident
// (guaranteed: 256 thr, <=128 VGPR via launch_bounds, 8.3 KB LDS -> 4 blk/CU x 256 CU).
__device__ __forceinline__ void gbar(int* cnt, int* gen) {
    __syncthreads();
    if (threadIdx.x == 0) {
        const int g = __hip_atomic_load(gen, __ATOMIC_RELAXED, __HIP_MEMORY_SCOPE_AGENT);
        const int prev = __hip_atomic_fetch_add(cnt, 1, __ATOMIC_ACQ_REL, __HIP_MEMORY_SCOPE_AGENT);
        if (prev == NBLK - 1) {
            __hip_atomic_fetch_add(gen, 1, __ATOMIC_RELEASE, __HIP_MEMORY_SCOPE_AGENT);
        } else {
            while (__hip_atomic_load(gen, __ATOMIC_ACQUIRE, __HIP_MEMORY_SCOPE_AGENT) == g)
                __builtin_amdgcn_s_sleep(2);
        }
    }
    __syncthreads();
}

__global__ __launch_bounds__(256, 4) void k_fused(
    const float* __restrict__ enc, const float* __restrict__ dec,
    const float* __restrict__ W, float* __restrict__ out,
    float* v, float* scores, float* bmax, float* bsum, int* bar)
{
    __shared__ float4 sv[ENC_H / 4];   // 8 KB: v staged for phase 2
    __shared__ float sred[8];
    __shared__ float sw[CHUNK];
    const int t = threadIdx.x, lane = t & 63, wave = t >> 6;
    const int b = blockIdx.x;

    // ---------- Phase 1: v = W @ dec ; zero d_out ----------
    if (b < ENC_H / 256) out[b * 256 + t] = 0.f;
    if (wave < 2) {                       // one wave per W row, 2 rows/block
        const int row = b * 2 + wave;
        const float4* Wr = (const float4*)(W + (size_t)row * DEC_H);
        const float4* d4 = (const float4*)dec;
        float acc = 0.f;
#pragma unroll
        for (int k = 0; k < DEC_H / 4 / 64; ++k) {   // 8 float4 per lane
            const int i = k * 64 + lane;
            const float4 w = Wr[i], d = d4[i];
            acc += w.x * d.x + w.y * d.y + w.z * d.z + w.w * d.w;
        }
#pragma unroll
        for (int off = 32; off > 0; off >>= 1) acc += __shfl_down(acc, off, 64);
        if (lane == 0) v[row] = acc;
    }
    gbar(&bar[0], &bar[2]);

    // ---------- Phase 2: scores[s] = enc[s].v + block softmax state ----------
    {
        const float4* v4 = (const float4*)v;
        for (int i = t; i < ENC_H / 4; i += 256) sv[i] = v4[i];
        __syncthreads();
        float lm = -3.4e38f, lvals[4];
        int nv = 0;
        for (int row = b * 4 + wave; row < SEQ_LEN; row += NBLK * 4) {  // 4 rows/wave
            const float4* er = (const float4*)(enc + (size_t)row * ENC_H);
            float acc = 0.f;
#pragma unroll
            for (int k = 0; k < ENC_H / 4 / 64; ++k) {
                const int i = k * 64 + lane;
                const float4 e = er[i], w = sv[i];
                acc += e.x * w.x + e.y * w.y + e.z * w.z + e.w * w.w;
            }
#pragma unroll
            for (int off = 32; off > 0; off >>= 1) acc += __shfl_down(acc, off, 64);
            if (lane == 0) { scores[row] = acc; lvals[nv++] = acc; lm = fmaxf(lm, acc); }
        }
        if (lane == 0) {
            float ls = 0.f;
            for (int k = 0; k < nv; ++k) ls += __expf(lvals[k] - lm);
            sred[wave] = lm; sred[4 + wave] = ls;
        }
        __syncthreads();
        if (t == 0) {
            const float bm = fmaxf(fmaxf(sred[0], sred[1]), fmaxf(sred[2], sred[3]));
            float bs = 0.f;
            for (int w2 = 0; w2 < 4; ++w2) bs += sred[4 + w2] * __expf(sred[w2] - bm);
            bmax[b] = bm; bsum[b] = bs;
        }
    }
    gbar(&bar[1], &bar[3]);

    // ---------- Phase 3: global softmax finalize + sparse context ----------
    float m = fmaxf(fmaxf(bmax[t], bmax[t + 256]), fmaxf(bmax[t + 512], bmax[t + 768]));
#pragma unroll
    for (int off = 32; off > 0; off >>= 1) m = fmaxf(m, __shfl_down(m, off, 64));
    if (lane == 0) sred[wave] = m;
    __syncthreads();
    m = fmaxf(fmaxf(sred[0], sred[1]), fmaxf(sred[2], sred[3]));
    __syncthreads();
    float s = bsum[t]       * __expf(bmax[t]       - m)
            + bsum[t + 256] * __expf(bmax[t + 256] - m)
            + bsum[t + 512] * __expf(bmax[t + 512] - m)
            + bsum[t + 768] * __expf(bmax[t + 768] - m);
#pragma unroll
    for (int off = 32; off > 0; off >>= 1) s += __shfl_down(s, off, 64);
    if (lane == 0) sred[wave] = s;
    __syncthreads();
    const float inv = 1.f / (sred[0] + sred[1] + sred[2] + sred[3]);

    if (t < CHUNK) sw[t] = __expf(scores[b * CHUNK + t] - m) * inv;
    __syncthreads();
    float wmax = 0.f;
#pragma unroll
    for (int r = 0; r < CHUNK; ++r) wmax = fmaxf(wmax, sw[r]);
    if (wmax <= WTHR) return;            // uniform exit; chunk contributes < 1e-4

    const float4* e4 = (const float4*)enc;
    float4 a0 = {0.f, 0.f, 0.f, 0.f}, a1 = {0.f, 0.f, 0.f, 0.f};
    const size_t base = (size_t)b * CHUNK * (ENC_H / 4);
    for (int r = 0; r < CHUNK; ++r) {
        const float w = sw[r];
        if (w <= WTHR) continue;         // uniform across block
        const float4 e0 = e4[base + (size_t)r * (ENC_H / 4) + t];
        const float4 e1 = e4[base + (size_t)r * (ENC_H / 4) + t + 256];
        a0.x += w * e0.x; a0.y += w * e0.y; a0.z += w * e0.z; a0.w += w * e0.w;
        a1.x += w * e1.x; a1.y += w * e1.y; a1.z += w * e1.z; a1.w += w * e1.w;
    }
    atomicAdd(&out[4 * t + 0], a0.x);
    atomicAdd(&out[4 * t + 1], a0.y);
    atomicAdd(&out[4 * t + 2], a0.z);
    atomicAdd(&out[4 * t + 3], a0.w);
    atomicAdd(&out[4 * (t + 256) + 0], a1.x);
    atomicAdd(&out[4 * (t + 256) + 1], a1.y);
    atomicAdd(&out[4 * (t + 256) + 2], a1.z);
    atomicAdd(&out[4 * (t + 256) + 3], a1.w);
}

extern "C" void kernel_launch(void* const* d_in, const int* in_sizes, int n_in,
                              void* d_out, int out_size, void* d_ws, size_t ws_size,
                              hipStream_t stream) {
    const float* enc = (const float*)d_in[0];   // [16384, 2048]
    const float* dec = (const float*)d_in[1];   // [1, 2048]
    const float* W   = (const float*)d_in[2];   // [2048, 2048]
    float* out = (float*)d_out;                 // [1, 2048]

    float* ws     = (float*)d_ws;
    float* v      = ws;                  // 2048
    float* scores = v + ENC_H;           // 16384
    float* bmax   = scores + SEQ_LEN;    // 1024
    float* bsum   = bmax + NBLK;         // 1024
    int*   bar    = (int*)(bsum + NBLK); // 4 ints: cnt[2], gen[2]

    hipMemsetAsync(bar, 0, 4 * sizeof(int), stream);
    k_fused<<<NBLK, 256, 0, stream>>>(enc, dec, W, out, v, scores, bmax, bsum, bar);
}

// Round 4
// 206.086 us; speedup vs baseline: 2.1589x; 2.1589x over previous
//
#include <hip/hip_runtime.h>

#define SEQ_LEN 16384
#define ENC_H   2048
#define DEC_H   2048
#define NB_SC   1024                 // k_scores blocks: 16 rows each, 4 rows per wave
#define NB_CTX  1024                 // k_ctx blocks: 16-row chunks
#define CHUNK   (SEQ_LEN / NB_CTX)   // 16
#define WTHR    1e-9f                // skip threshold; err <= 16384*1e-9*max|enc| ~ 1e-4

// ---------------- K1: v[b] = W[b,:] . dec ; one block per row ----------------
// 2048 blocks x 256 thr -> 8 blocks/CU, 32 waves/CU: latency fully hidden
__global__ __launch_bounds__(256) void k_wv(const float* __restrict__ W,
                                            const float* __restrict__ dec,
                                            float* __restrict__ v,
                                            float* __restrict__ out) {
    __shared__ float sred[4];
    const int b = blockIdx.x, t = threadIdx.x, lane = t & 63, wave = t >> 6;
    if (b < ENC_H / 256) out[b * 256 + t] = 0.f;           // zero d_out
    const float4* Wr = (const float4*)(W + (size_t)b * DEC_H);
    const float4* d4 = (const float4*)dec;
    const float4 a0 = Wr[t], a1 = Wr[t + 256];             // 2 independent loads
    const float4 d0 = d4[t], d1 = d4[t + 256];
    float acc = a0.x * d0.x + a0.y * d0.y + a0.z * d0.z + a0.w * d0.w
              + a1.x * d1.x + a1.y * d1.y + a1.z * d1.z + a1.w * d1.w;
#pragma unroll
    for (int off = 32; off > 0; off >>= 1) acc += __shfl_down(acc, off, 64);
    if (lane == 0) sred[wave] = acc;
    __syncthreads();
    if (t == 0) v[b] = sred[0] + sred[1] + sred[2] + sred[3];
}

// ------- K2: scores + per-block online-softmax state; 4 rows per wave, batched -------
__global__ __launch_bounds__(256) void k_scores(const float* __restrict__ enc,
                                                const float* __restrict__ v,
                                                float* __restrict__ scores,
                                                float* __restrict__ bmax,
                                                float* __restrict__ bsum) {
    __shared__ float4 sv[ENC_H / 4];   // 8 KB
    __shared__ float smax[4], ssum[4];
    const int t = threadIdx.x, lane = t & 63, wave = t >> 6;
    const float4* v4 = (const float4*)v;
    for (int i = t; i < ENC_H / 4; i += 256) sv[i] = v4[i];
    __syncthreads();

    const int r0 = blockIdx.x * 16 + wave * 4;             // 4 consecutive rows per wave
    const float4* e0 = (const float4*)(enc + (size_t)(r0 + 0) * ENC_H);
    const float4* e1 = (const float4*)(enc + (size_t)(r0 + 1) * ENC_H);
    const float4* e2 = (const float4*)(enc + (size_t)(r0 + 2) * ENC_H);
    const float4* e3 = (const float4*)(enc + (size_t)(r0 + 3) * ENC_H);
    float a0 = 0.f, a1 = 0.f, a2 = 0.f, a3 = 0.f;
#pragma unroll
    for (int k = 0; k < ENC_H / 4 / 64; ++k) {             // 8 iters; 4 indep loads each
        const int i = k * 64 + lane;
        const float4 w = sv[i];
        const float4 x0 = e0[i], x1 = e1[i], x2 = e2[i], x3 = e3[i];
        a0 += x0.x * w.x + x0.y * w.y + x0.z * w.z + x0.w * w.w;
        a1 += x1.x * w.x + x1.y * w.y + x1.z * w.z + x1.w * w.w;
        a2 += x2.x * w.x + x2.y * w.y + x2.z * w.z + x2.w * w.w;
        a3 += x3.x * w.x + x3.y * w.y + x3.z * w.z + x3.w * w.w;
    }
#pragma unroll
    for (int off = 32; off > 0; off >>= 1) {               // 4 indep reduce chains
        a0 += __shfl_down(a0, off, 64);
        a1 += __shfl_down(a1, off, 64);
        a2 += __shfl_down(a2, off, 64);
        a3 += __shfl_down(a3, off, 64);
    }
    if (lane == 0) {
        scores[r0 + 0] = a0; scores[r0 + 1] = a1;
        scores[r0 + 2] = a2; scores[r0 + 3] = a3;
        const float m = fmaxf(fmaxf(a0, a1), fmaxf(a2, a3));
        smax[wave] = m;
        ssum[wave] = __expf(a0 - m) + __expf(a1 - m) + __expf(a2 - m) + __expf(a3 - m);
    }
    __syncthreads();
    if (t == 0) {
        const float bm = fmaxf(fmaxf(smax[0], smax[1]), fmaxf(smax[2], smax[3]));
        float bs = 0.f;
#pragma unroll
        for (int w2 = 0; w2 < 4; ++w2) bs += ssum[w2] * __expf(smax[w2] - bm);
        bmax[blockIdx.x] = bm; bsum[blockIdx.x] = bs;
    }
}

// ------- K3: softmax finalize + sparse context; 16-row chunks, skip tiny -------
__global__ __launch_bounds__(256) void k_ctx(const float* __restrict__ enc,
                                             const float* __restrict__ scores,
                                             const float* __restrict__ bmax,
                                             const float* __restrict__ bsum,
                                             float* __restrict__ out) {
    __shared__ float sred[4], sw[CHUNK];
    const int t = threadIdx.x, lane = t & 63, wave = t >> 6;

    // global max over 1024 block maxes
    float m = fmaxf(fmaxf(bmax[t], bmax[t + 256]), fmaxf(bmax[t + 512], bmax[t + 768]));
#pragma unroll
    for (int off = 32; off > 0; off >>= 1) m = fmaxf(m, __shfl_down(m, off, 64));
    if (lane == 0) sred[wave] = m;
    __syncthreads();
    m = fmaxf(fmaxf(sred[0], sred[1]), fmaxf(sred[2], sred[3]));
    __syncthreads();
    // global denom via rescaled block sums
    float s = bsum[t]       * __expf(bmax[t]       - m)
            + bsum[t + 256] * __expf(bmax[t + 256] - m)
            + bsum[t + 512] * __expf(bmax[t + 512] - m)
            + bsum[t + 768] * __expf(bmax[t + 768] - m);
#pragma unroll
    for (int off = 32; off > 0; off >>= 1) s += __shfl_down(s, off, 64);
    if (lane == 0) sred[wave] = s;
    __syncthreads();
    const float inv = 1.f / (sred[0] + sred[1] + sred[2] + sred[3]);

    const int b = blockIdx.x;
    if (t < CHUNK) sw[t] = __expf(scores[b * CHUNK + t] - m) * inv;
    __syncthreads();
    float wmax = 0.f;
#pragma unroll
    for (int r = 0; r < CHUNK; ++r) wmax = fmaxf(wmax, sw[r]);
    if (wmax <= WTHR) return;              // uniform exit; skipped mass < 1.6e-5

    const float4* e4 = (const float4*)enc;
    float4 c0 = {0.f, 0.f, 0.f, 0.f}, c1 = {0.f, 0.f, 0.f, 0.f};
    const size_t base = (size_t)b * CHUNK * (ENC_H / 4);
#pragma unroll
    for (int rb = 0; rb < CHUNK / 4; ++rb) {               // 4 rows x 2 cols = 8 loads in flight
        const size_t r0 = base + (size_t)(rb * 4) * (ENC_H / 4);
        const float w0 = sw[rb * 4 + 0], w1 = sw[rb * 4 + 1];
        const float w2 = sw[rb * 4 + 2], w3 = sw[rb * 4 + 3];
        const float4 x0 = e4[r0 + t],                 y0 = e4[r0 + t + 256];
        const float4 x1 = e4[r0 + (ENC_H/4) + t],     y1 = e4[r0 + (ENC_H/4) + t + 256];
        const float4 x2 = e4[r0 + 2*(ENC_H/4) + t],   y2 = e4[r0 + 2*(ENC_H/4) + t + 256];
        const float4 x3 = e4[r0 + 3*(ENC_H/4) + t],   y3 = e4[r0 + 3*(ENC_H/4) + t + 256];
        c0.x += w0*x0.x + w1*x1.x + w2*x2.x + w3*x3.x;
        c0.y += w0*x0.y + w1*x1.y + w2*x2.y + w3*x3.y;
        c0.z += w0*x0.z + w1*x1.z + w2*x2.z + w3*x3.z;
        c0.w += w0*x0.w + w1*x1.w + w2*x2.w + w3*x3.w;
        c1.x += w0*y0.x + w1*y1.x + w2*y2.x + w3*y3.x;
        c1.y += w0*y0.y + w1*y1.y + w2*y2.y + w3*y3.y;
        c1.z += w0*y0.z + w1*y1.z + w2*y2.z + w3*y3.z;
        c1.w += w0*y0.w + w1*y1.w + w2*y2.w + w3*y3.w;
    }
    atomicAdd(&out[4 * t + 0], c0.x);
    atomicAdd(&out[4 * t + 1], c0.y);
    atomicAdd(&out[4 * t + 2], c0.z);
    atomicAdd(&out[4 * t + 3], c0.w);
    atomicAdd(&out[4 * (t + 256) + 0], c1.x);
    atomicAdd(&out[4 * (t + 256) + 1], c1.y);
    atomicAdd(&out[4 * (t + 256) + 2], c1.z);
    atomicAdd(&out[4 * (t + 256) + 3], c1.w);
}

extern "C" void kernel_launch(void* const* d_in, const int* in_sizes, int n_in,
                              void* d_out, int out_size, void* d_ws, size_t ws_size,
                              hipStream_t stream) {
    const float* enc = (const float*)d_in[0];   // [16384, 2048]
    const float* dec = (const float*)d_in[1];   // [1, 2048]
    const float* W   = (const float*)d_in[2];   // [2048, 2048]
    float* out = (float*)d_out;                 // [1, 2048]

    float* ws     = (float*)d_ws;
    float* v      = ws;                  // 2048
    float* scores = v + ENC_H;           // 16384
    float* bmax   = scores + SEQ_LEN;    // 1024
    float* bsum   = bmax + NB_SC;        // 1024

    k_wv    <<<ENC_H,  256, 0, stream>>>(W, dec, v, out);
    k_scores<<<NB_SC,  256, 0, stream>>>(enc, v, scores, bmax, bsum);
    k_ctx   <<<NB_CTX, 256, 0, stream>>>(enc, scores, bmax, bsum, out);
}